// Round 3
// baseline (217.043 us; speedup 1.0000x reference)
//
#include <hip/hip_runtime.h>
#include <hip/hip_bf16.h>

// Quantized int8 3x3 conv via implicit-im2col MFMA (mfma_i32_16x16x64_i8).
// out = 1e-4*dot + asumf[px] + bconst[co]
//
// Round-3 structure:
//   wq2 step-major [tap][q8][co256][16B]  -> A staging = contiguous global_load_lds
//   B operand: direct global->reg fragments (16 px x 64B = 16 full lines / load)
//   tile 128co x 128px, BK=128 (1 tap), A-only LDS dbuf 32KB -> 5 blocks/CU

#define N_B   32
#define C_IN  128
#define H_IN  56
#define W_IN  56
#define C_OUT 256
#define H_OUT 54
#define W_OUT 54
#define K_TOT 1152
#define NPX   (N_B * H_OUT * W_OUT)   // 93312
#define PXROW (H_OUT * W_OUT)         // 2916

using i32x4 = __attribute__((ext_vector_type(4))) int;

static __device__ __forceinline__ int dot4(int a, int b, int c) {
#if __has_builtin(__builtin_amdgcn_sdot4)
  return __builtin_amdgcn_sdot4(a, b, c, false);
#else
  signed char a0 = (signed char)a, a1 = (signed char)(a >> 8),
              a2 = (signed char)(a >> 16), a3 = (signed char)(a >> 24);
  signed char b0 = (signed char)b, b1 = (signed char)(b >> 8),
              b2 = (signed char)(b >> 16), b3 = (signed char)(b >> 24);
  return c + a0 * b0 + a1 * b1 + a2 * b2 + a3 * b3;
#endif
}

__device__ __forceinline__ void gload16(const void* g, void* l) {
  __builtin_amdgcn_global_load_lds(
      (const __attribute__((address_space(1))) void*)g,
      (__attribute__((address_space(3))) void*)l, 16, 0, 0);
}

// ---------------- weight repack: OIHW(int32) -> wq2[t][q][co][16] i8, bconst
__global__ void repack_w(const int* __restrict__ w, const float* __restrict__ bias,
                         signed char* __restrict__ wq2, float* __restrict__ bconst) {
  int co = blockIdx.x;    // 256
  int ci = threadIdx.x;   // 128
  const int* wrow = w + (size_t)co * K_TOT + (size_t)ci * 9;
  int s = 0;
  int q = ci >> 4, b = ci & 15;
#pragma unroll
  for (int t = 0; t < 9; ++t) {
    int v = wrow[t];
    s += v;
    wq2[(size_t)t * 32768 + q * 4096 + co * 16 + b] = (signed char)v;
  }
  __shared__ int red[128];
  red[ci] = s;
  __syncthreads();
  for (int off = 64; off > 0; off >>= 1) {
    if (ci < off) red[ci] += red[ci + off];
    __syncthreads();
  }
  if (ci == 0) {
    int wsum = red[0];
    float r = rintf(bias[co] / 0.0001f);                 // round half-even
    r = fminf(fmaxf(r, -2147483648.0f), 2147483647.0f);  // clamp to i32 range
    bconst[co] = 1e-4f * (float)(-7 * wsum + 24192) + r * 0.0001f;
  }
}

// ---------------- input repack: NCHW(int32) -> NHWC int8, fused per-px channel sums
__global__ void repack_in(const int* __restrict__ in, signed char* __restrict__ ip,
                          int* __restrict__ rs) {
  __shared__ int t32[C_IN * W_IN];   // 28KB
  __shared__ int rsum[W_IN];
  int h = blockIdx.x, n = blockIdx.y;
  int tid = threadIdx.x;
  if (tid < W_IN) rsum[tid] = 0;

  // load phase: thread (ci = tid>>1, half = tid&1) reads 28 dwords
  int ci = tid >> 1, hf = tid & 1;
  const int* s = in + ((size_t)n * C_IN + ci) * (H_IN * W_IN) + h * W_IN + hf * 28;
  int* d = &t32[ci * W_IN + hf * 28];
#pragma unroll
  for (int k = 0; k < 7; ++k)
    *(int4*)(d + k * 4) = *(const int4*)(s + k * 4);
  __syncthreads();

  // store phase: 448 int4 outputs, fully coalesced; fold channel sums
  signed char* dst = ip + (((size_t)n * H_IN + h) * W_IN) * C_IN;
  for (int j = tid; j < 448; j += 256) {
    int w = j >> 3, c16 = j & 7;
    int b[4], srow = 0;
#pragma unroll
    for (int q = 0; q < 4; ++q) {
      int x0 = t32[(c16 * 16 + q * 4 + 0) * W_IN + w];
      int x1 = t32[(c16 * 16 + q * 4 + 1) * W_IN + w];
      int x2 = t32[(c16 * 16 + q * 4 + 2) * W_IN + w];
      int x3 = t32[(c16 * 16 + q * 4 + 3) * W_IN + w];
      b[q] = (x0 & 255) | ((x1 & 255) << 8) | ((x2 & 255) << 16) | ((x3 & 255) << 24);
      srow = dot4(b[q], 0x01010101, srow);
    }
    *(int4*)(dst + (size_t)j * 16) = *(int4*)b;
    atomicAdd(&rsum[w], srow);
  }
  __syncthreads();
  if (tid < W_IN) rs[((size_t)n * H_IN + h) * W_IN + tid] = rsum[tid];
}

// ---------------- per-output-pixel: asumf = -3e-4 * rf-sum, lut = out dword off (co=0)
__global__ void asum_lut(const int* __restrict__ rs, float* __restrict__ asumf,
                         int* __restrict__ lutdw) {
  int px = blockIdx.x * 256 + threadIdx.x;
  if (px >= NPX) return;
  int n = px / PXROW, rem = px - n * PXROW;
  int y = rem / W_OUT, x = rem - y * W_OUT;
  const int* rp = rs + ((size_t)n * H_IN + y) * W_IN + x;
  int s = 0;
#pragma unroll
  for (int kh = 0; kh < 3; ++kh)
    s += rp[kh * W_IN + 0] + rp[kh * W_IN + 1] + rp[kh * W_IN + 2];
  asumf[px] = -3e-4f * (float)s;
  lutdw[px] = n * (C_OUT * PXROW) + y * W_OUT + x;
}

// ---------------- main MFMA conv
// grid (729 px-tiles, 2 co-tiles), 256 thr (4 waves, 2co x 2px).
// LDS: A dbuf 2x16KB, layout [q(8)][co(128)][16B] per buffer.
__launch_bounds__(256, 5)
__global__ void conv_mfma(const signed char* __restrict__ ip,
                          const signed char* __restrict__ wq2,
                          const float* __restrict__ asumf,
                          const int* __restrict__ lutdw,
                          const float* __restrict__ bconst,
                          float* __restrict__ out) {
  __shared__ signed char lds[32768];
  const int tid = threadIdx.x, w = tid >> 6, l = tid & 63;
  const int wr = w >> 1, wc = w & 1;
  const int pxb = blockIdx.x * 128;
  const int ctile = blockIdx.y;

  // input byte offset of tap t within a pixel's receptive field
  constexpr int TOFF[9] = {
      0 * W_IN * C_IN + 0 * C_IN, 0 * W_IN * C_IN + 1 * C_IN, 0 * W_IN * C_IN + 2 * C_IN,
      1 * W_IN * C_IN + 0 * C_IN, 1 * W_IN * C_IN + 1 * C_IN, 1 * W_IN * C_IN + 2 * C_IN,
      2 * W_IN * C_IN + 0 * C_IN, 2 * W_IN * C_IN + 1 * C_IN, 2 * W_IN * C_IN + 2 * C_IN};

  // B fragment bases: px = pxb + wc*64 + p*16 + (l&15), k-byte = (l>>4)*16
  const signed char* bbase[4];
#pragma unroll
  for (int p = 0; p < 4; ++p) {
    int px = pxb + wc * 64 + p * 16 + (l & 15);
    int n = px / PXROW, rem = px - n * PXROW;
    int y = rem / W_OUT, x = rem - y * W_OUT;
    bbase[p] = ip + ((size_t)((n * H_IN + y) * W_IN + x)) * C_IN + ((l >> 4) * 16);
  }

  // A staging: instr j: q = w*2 + (j>>1), ch = j&1
  const signed char* asrc = wq2 + ctile * 2048 + (size_t)l * 16;
  // A fragment read base: + cb*16384 + kk*8192 + m*256
  const int afbase = (l >> 4) * 2048 + (wr * 64 + (l & 15)) * 16;

#define STAGE_A(t, nb)                                                          \
  {                                                                             \
    _Pragma("unroll") for (int j = 0; j < 4; ++j) {                             \
      int q = w * 2 + (j >> 1), ch = j & 1;                                     \
      gload16(asrc + (size_t)(t) * 32768 + q * 4096 + ch * 1024,                \
              &lds[(nb) * 16384 + q * 2048 + ch * 1024]);                       \
    }                                                                           \
  }
#define LOAD_B(t, d)                                                            \
  {                                                                             \
    _Pragma("unroll") for (int kk = 0; kk < 2; ++kk)                            \
        _Pragma("unroll") for (int p = 0; p < 4; ++p)                           \
            brg[d][kk][p] = *(const i32x4*)(bbase[p] + TOFF[t] + kk * 64);      \
  }

  i32x4 acc[4][4];
#pragma unroll
  for (int m = 0; m < 4; ++m)
#pragma unroll
    for (int p = 0; p < 4; ++p) acc[m][p] = (i32x4){0, 0, 0, 0};

  i32x4 brg[2][2][4];
  STAGE_A(0, 0);
  LOAD_B(0, 0);
  __syncthreads();

#pragma unroll
  for (int t = 0; t < 9; ++t) {
    const int cb = t & 1, nb = cb ^ 1;
    if (t < 8) {
      STAGE_A(t + 1, nb);
      LOAD_B(t + 1, nb);
    }
#pragma unroll
    for (int kk = 0; kk < 2; ++kk) {
      i32x4 af[4];
#pragma unroll
      for (int m = 0; m < 4; ++m)
        af[m] = *(const i32x4*)(lds + cb * 16384 + afbase + kk * 8192 + m * 256);
#pragma unroll
      for (int m = 0; m < 4; ++m)
#pragma unroll
        for (int p = 0; p < 4; ++p)
          acc[m][p] = __builtin_amdgcn_mfma_i32_16x16x64_i8(af[m], brg[cb][kk][p],
                                                            acc[m][p], 0, 0, 0);
    }
    if (t < 8) __syncthreads();
  }

  // epilogue: C frag 16x16: col px = lane&15, row co = (lane>>4)*4 + j
  const int colpx = pxb + wc * 64 + (l & 15);
  int lut[4]; float asf[4];
#pragma unroll
  for (int p = 0; p < 4; ++p) {
    lut[p] = lutdw[colpx + 16 * p];
    asf[p] = asumf[colpx + 16 * p];
  }
#pragma unroll
  for (int m = 0; m < 4; ++m) {
#pragma unroll
    for (int j = 0; j < 4; ++j) {
      int co = ctile * 128 + wr * 64 + m * 16 + (l >> 4) * 4 + j;
      float bc = bconst[co];
      float* ob = out + (size_t)co * PXROW;
#pragma unroll
      for (int p = 0; p < 4; ++p)
        ob[lut[p]] = 1e-4f * (float)acc[m][p][j] + asf[p] + bc;
    }
  }
#undef STAGE_A
#undef LOAD_B
}

// ---------------- fallback (tiny ws): naive direct conv
__global__ void conv_naive(const int* __restrict__ in, const int* __restrict__ w,
                           const float* __restrict__ bias, float* __restrict__ out) {
  size_t idx = (size_t)blockIdx.x * 256 + threadIdx.x;
  size_t total = (size_t)N_B * C_OUT * H_OUT * W_OUT;
  if (idx >= total) return;
  int x = idx % W_OUT; size_t t = idx / W_OUT;
  int y = t % H_OUT; t /= H_OUT;
  int co = t % C_OUT; int n = (int)(t / C_OUT);
  int acc = 0;
  for (int ci = 0; ci < C_IN; ++ci) {
    const int* ib = in + (((size_t)n * C_IN + ci) * H_IN + y) * W_IN + x;
    const int* wb = w + (((size_t)co * C_IN + ci) * 3) * 3;
    for (int kh = 0; kh < 3; ++kh)
      for (int kw = 0; kw < 3; ++kw)
        acc += (ib[kh * W_IN + kw] - 7) * (wb[kh * 3 + kw] - 3);
  }
  float r = rintf(bias[co] / 0.0001f);
  r = fminf(fmaxf(r, -2147483648.0f), 2147483647.0f);
  out[idx] = (float)acc * (0.01f * 0.01f) + r * 0.0001f;
}

extern "C" void kernel_launch(void* const* d_in, const int* in_sizes, int n_in,
                              void* d_out, int out_size, void* d_ws, size_t ws_size,
                              hipStream_t stream) {
  const int*   in   = (const int*)d_in[0];
  const int*   w    = (const int*)d_in[1];
  const float* bias = (const float*)d_in[2];
  float*       out  = (float*)d_out;

  const size_t WQ_OFF = 0;                        // 9*8*256*16 i8    = 294912
  const size_t IP_OFF = 294912;                   // 32*56*56*128 i8  = 12845056
  const size_t RS_OFF = IP_OFF + 12845056;        // 32*56*56 i32     = 401408
  const size_t AF_OFF = RS_OFF + 401408;          // 93312 f32        = 373248
  const size_t LU_OFF = AF_OFF + 373248;          // 93312 i32        = 373248
  const size_t BC_OFF = LU_OFF + 373248;          // 256 f32
  const size_t NEED   = BC_OFF + 1024;

  if (ws_size >= NEED) {
    char* ws = (char*)d_ws;
    signed char* wq2  = (signed char*)(ws + WQ_OFF);
    signed char* ip   = (signed char*)(ws + IP_OFF);
    int*         rs   = (int*)(ws + RS_OFF);
    float*       af   = (float*)(ws + AF_OFF);
    int*         lu   = (int*)(ws + LU_OFF);
    float*       bc   = (float*)(ws + BC_OFF);

    repack_w<<<C_OUT, 128, 0, stream>>>(w, bias, wq2, bc);
    repack_in<<<dim3(H_IN, N_B), 256, 0, stream>>>(in, ip, rs);
    asum_lut<<<(NPX + 255) / 256, 256, 0, stream>>>(rs, af, lu);
    conv_mfma<<<dim3(NPX / 128, 2), 256, 0, stream>>>(ip, wq2, af, lu, bc, out);
  } else {
    size_t total = (size_t)N_B * C_OUT * H_OUT * W_OUT;
    conv_naive<<<(total + 255) / 256, 256, 0, stream>>>(in, w, bias, out);
  }
}

// Round 4
// 73.707 us; speedup vs baseline: 2.9447x; 2.9447x over previous
//
#include <hip/hip_runtime.h>
#include <hip/hip_bf16.h>

// Quantized int8 3x3 conv via implicit-im2col MFMA (mfma_i32_16x16x64_i8).
// out = 1e-4*dot + asumf[px] + bconst[co]
//
// Round-4 structure:
//   - block owns 2 output rows (108 px) x 128 couts; grid (27 rowpairs, 32 n, 2 ctile)
//   - input slab (4 rows x 56 x 128 = 28KB) staged ONCE per block, XOR-swizzled
//     (pre-swizzled global source + linear LDS dest; readers apply same XOR)
//   - weights step-major wq2[tap][q8][co256][16B]: contiguous global_load_lds,
//     per-tap 16KB double-buffered
//   - 4 waves (2co x 2px), each m4 x p4 x kk2 = 32 MFMA per tap

#define N_B   32
#define C_IN  128
#define H_IN  56
#define W_IN  56
#define C_OUT 256
#define H_OUT 54
#define W_OUT 54
#define K_TOT 1152
#define NPX   (N_B * H_OUT * W_OUT)   // 93312
#define PXROW (H_OUT * W_OUT)         // 2916

#define AOFF  28672                   // A dbuf base in LDS (after 28KB B slab)

using i32x4 = __attribute__((ext_vector_type(4))) int;

static __device__ __forceinline__ int dot4(int a, int b, int c) {
#if __has_builtin(__builtin_amdgcn_sdot4)
  return __builtin_amdgcn_sdot4(a, b, c, false);
#else
  signed char a0 = (signed char)a, a1 = (signed char)(a >> 8),
              a2 = (signed char)(a >> 16), a3 = (signed char)(a >> 24);
  signed char b0 = (signed char)b, b1 = (signed char)(b >> 8),
              b2 = (signed char)(b >> 16), b3 = (signed char)(b >> 24);
  return c + a0 * b0 + a1 * b1 + a2 * b2 + a3 * b3;
#endif
}

__device__ __forceinline__ void gload16(const void* g, void* l) {
  __builtin_amdgcn_global_load_lds(
      (const __attribute__((address_space(1))) void*)g,
      (__attribute__((address_space(3))) void*)l, 16, 0, 0);
}

// ---------------- weight repack: OIHW(int32) -> wq2[t][q][co][16] i8, bconst
__global__ void repack_w(const int* __restrict__ w, const float* __restrict__ bias,
                         signed char* __restrict__ wq2, float* __restrict__ bconst) {
  int co = blockIdx.x;    // 256
  int ci = threadIdx.x;   // 128
  const int* wrow = w + (size_t)co * K_TOT + (size_t)ci * 9;
  int s = 0;
  int q = ci >> 4, b = ci & 15;
#pragma unroll
  for (int t = 0; t < 9; ++t) {
    int v = wrow[t];
    s += v;
    wq2[(size_t)t * 32768 + q * 4096 + co * 16 + b] = (signed char)v;
  }
  __shared__ int red[128];
  red[ci] = s;
  __syncthreads();
  for (int off = 64; off > 0; off >>= 1) {
    if (ci < off) red[ci] += red[ci + off];
    __syncthreads();
  }
  if (ci == 0) {
    int wsum = red[0];
    float r = rintf(bias[co] / 0.0001f);                 // round half-even
    r = fminf(fmaxf(r, -2147483648.0f), 2147483647.0f);  // clamp to i32 range
    bconst[co] = 1e-4f * (float)(-7 * wsum + 24192) + r * 0.0001f;
  }
}

// ---------------- input repack: NCHW(int32) -> NHWC int8, fused per-px channel sums
__global__ void repack_in(const int* __restrict__ in, signed char* __restrict__ ip,
                          int* __restrict__ rs) {
  __shared__ int t32[C_IN * W_IN];   // 28KB
  __shared__ int rsum[W_IN];
  int h = blockIdx.x, n = blockIdx.y;
  int tid = threadIdx.x;
  if (tid < W_IN) rsum[tid] = 0;

  int ci = tid >> 1, hf = tid & 1;
  const int* s = in + ((size_t)n * C_IN + ci) * (H_IN * W_IN) + h * W_IN + hf * 28;
  int* d = &t32[ci * W_IN + hf * 28];
#pragma unroll
  for (int k = 0; k < 7; ++k)
    *(int4*)(d + k * 4) = *(const int4*)(s + k * 4);
  __syncthreads();

  signed char* dst = ip + (((size_t)n * H_IN + h) * W_IN) * C_IN;
  for (int j = tid; j < 448; j += 256) {
    int w = j >> 3, c16 = j & 7;
    int b[4], srow = 0;
#pragma unroll
    for (int q = 0; q < 4; ++q) {
      int x0 = t32[(c16 * 16 + q * 4 + 0) * W_IN + w];
      int x1 = t32[(c16 * 16 + q * 4 + 1) * W_IN + w];
      int x2 = t32[(c16 * 16 + q * 4 + 2) * W_IN + w];
      int x3 = t32[(c16 * 16 + q * 4 + 3) * W_IN + w];
      b[q] = (x0 & 255) | ((x1 & 255) << 8) | ((x2 & 255) << 16) | ((x3 & 255) << 24);
      srow = dot4(b[q], 0x01010101, srow);
    }
    *(int4*)(dst + (size_t)j * 16) = *(int4*)b;
    atomicAdd(&rsum[w], srow);
  }
  __syncthreads();
  if (tid < W_IN) rs[((size_t)n * H_IN + h) * W_IN + tid] = rsum[tid];
}

// ---------------- per-output-pixel: asumf = -3e-4 * receptive-field sum
__global__ void asum_k(const int* __restrict__ rs, float* __restrict__ asumf) {
  int px = blockIdx.x * 256 + threadIdx.x;
  if (px >= NPX) return;
  int n = px / PXROW, rem = px - n * PXROW;
  int y = rem / W_OUT, x = rem - y * W_OUT;
  const int* rp = rs + ((size_t)n * H_IN + y) * W_IN + x;
  int s = 0;
#pragma unroll
  for (int kh = 0; kh < 3; ++kh)
    s += rp[kh * W_IN + 0] + rp[kh * W_IN + 1] + rp[kh * W_IN + 2];
  asumf[px] = -3e-4f * (float)s;
}

// ---------------- main MFMA conv
__launch_bounds__(256, 2)
__global__ void conv_mfma(const signed char* __restrict__ ip,
                          const signed char* __restrict__ wq2,
                          const float* __restrict__ asumf,
                          const float* __restrict__ bconst,
                          float* __restrict__ out) {
  __shared__ signed char lds[61440];  // B slab [0,28672) + A dbuf 2x16KB
  const int tid = threadIdx.x, w = tid >> 6, l = tid & 63;
  const int wr = w >> 1, wc = w & 1;
  const int rp = blockIdx.x;           // row pair 0..26
  const int n  = blockIdx.y;           // 0..31
  const int ct = blockIdx.z;           // co tile 0..1
  const int y0 = rp * 2;

  // ---- stage B slab (4 input rows, 28KB), pre-swizzled source, linear dest
  const signed char* slab = ip + ((size_t)(n * H_IN + y0) * W_IN) * C_IN;
  const int sw = ((tid >> 3) & 7) << 4;        // (L>>7)&7 is i-invariant
#pragma unroll
  for (int i = 0; i < 7; ++i) {
    int L = i * 4096 + tid * 16;
    gload16(slab + (L ^ sw), &lds[L]);
  }

  // ---- A staging: dest L = AOFF + nb*16384 + i*4096 + tid*16 (linear)
  //      src = wq2 + t*32768 + (i*2 + (tid>>7))*4096 + ct*2048 + (tid&127)*16
  const signed char* asrc =
      wq2 + (size_t)(tid >> 7) * 4096 + ct * 2048 + (size_t)(tid & 127) * 16;
#define STAGE_A(t, nb)                                                       \
  {                                                                          \
    _Pragma("unroll") for (int i = 0; i < 4; ++i)                            \
        gload16(asrc + (size_t)(t) * 32768 + i * 8192,                       \
                &lds[AOFF + (nb) * 16384 + i * 4096 + tid * 16]);            \
  }

  STAGE_A(0, 0);

  // ---- per-lane B pixel bases (slab px index for each fragment)
  // output px j = wc*64 + p*16 + (l&15); rows y0..y0+1 of width 54
  int psb[4];
#pragma unroll
  for (int p = 0; p < 4; ++p) {
    int j = wc * 64 + p * 16 + (l & 15);
    if (j > 107) j = 107;                 // dead lanes clamp (stores guarded)
    int dy = (j >= 54) ? 1 : 0;
    psb[p] = dy * 56 + (j - dy * 54);
  }
  const int c0 = (l >> 4) * 16;
  // A fragment lane base: co = wr*64 + m*16 + (l&15), kchunk = l>>4
  const int abase = AOFF + (l >> 4) * 2048 + (wr * 64 + (l & 15)) * 16;

  i32x4 acc[4][4];
#pragma unroll
  for (int m = 0; m < 4; ++m)
#pragma unroll
    for (int p = 0; p < 4; ++p) acc[m][p] = (i32x4){0, 0, 0, 0};

  __syncthreads();   // slab + A(0) staged (drains vmcnt)

#pragma unroll
  for (int t = 0; t < 9; ++t) {
    const int cb = t & 1, nb = cb ^ 1;
    if (t < 8) STAGE_A(t + 1, nb);
    const int dlt = (t / 3) * 56 + (t % 3);    // tap offset in slab px units
#pragma unroll
    for (int kk = 0; kk < 2; ++kk) {
      i32x4 af[4], bf[4];
#pragma unroll
      for (int m = 0; m < 4; ++m)
        af[m] = *(const i32x4*)(&lds[abase + cb * 16384 + kk * 8192 + m * 256]);
#pragma unroll
      for (int p = 0; p < 4; ++p) {
        int ps = psb[p] + dlt;
        int ad = ((ps << 7) + c0 + kk * 64) ^ ((ps & 7) << 4);
        bf[p] = *(const i32x4*)(&lds[ad]);
      }
#pragma unroll
      for (int m = 0; m < 4; ++m)
#pragma unroll
        for (int p = 0; p < 4; ++p)
          acc[m][p] = __builtin_amdgcn_mfma_i32_16x16x64_i8(af[m], bf[p],
                                                            acc[m][p], 0, 0, 0);
    }
    if (t < 8) __syncthreads();
  }

  // ---- epilogue: C frag: px col = l&15, co row = (l>>4)*4 + j
  float* obase = out + ((size_t)(n * C_OUT + ct * 128)) * PXROW + y0 * W_OUT;
  const float* apx = asumf + (size_t)n * PXROW + y0 * W_OUT;
  int jv[4]; float asf[4];
#pragma unroll
  for (int p = 0; p < 4; ++p) {
    int j = wc * 64 + p * 16 + (l & 15);
    jv[p] = j;
    asf[p] = (j < 108) ? apx[j] : 0.0f;
  }
#pragma unroll
  for (int m = 0; m < 4; ++m) {
#pragma unroll
    for (int jj = 0; jj < 4; ++jj) {
      int col = wr * 64 + m * 16 + (l >> 4) * 4 + jj;   // co within ctile
      float bc = bconst[ct * 128 + col];
      float* o = obase + (size_t)col * PXROW;
#pragma unroll
      for (int p = 0; p < 4; ++p)
        if (jv[p] < 108)
          o[jv[p]] = 1e-4f * (float)acc[m][p][jj] + asf[p] + bc;
    }
  }
#undef STAGE_A
}

// ---------------- fallback (tiny ws): naive direct conv
__global__ void conv_naive(const int* __restrict__ in, const int* __restrict__ w,
                           const float* __restrict__ bias, float* __restrict__ out) {
  size_t idx = (size_t)blockIdx.x * 256 + threadIdx.x;
  size_t total = (size_t)N_B * C_OUT * H_OUT * W_OUT;
  if (idx >= total) return;
  int x = idx % W_OUT; size_t t = idx / W_OUT;
  int y = t % H_OUT; t /= H_OUT;
  int co = t % C_OUT; int n = (int)(t / C_OUT);
  int acc = 0;
  for (int ci = 0; ci < C_IN; ++ci) {
    const int* ib = in + (((size_t)n * C_IN + ci) * H_IN + y) * W_IN + x;
    const int* wb = w + (((size_t)co * C_IN + ci) * 3) * 3;
    for (int kh = 0; kh < 3; ++kh)
      for (int kw = 0; kw < 3; ++kw)
        acc += (ib[kh * W_IN + kw] - 7) * (wb[kh * 3 + kw] - 3);
  }
  float r = rintf(bias[co] / 0.0001f);
  r = fminf(fmaxf(r, -2147483648.0f), 2147483647.0f);
  out[idx] = (float)acc * (0.01f * 0.01f) + r * 0.0001f;
}

extern "C" void kernel_launch(void* const* d_in, const int* in_sizes, int n_in,
                              void* d_out, int out_size, void* d_ws, size_t ws_size,
                              hipStream_t stream) {
  const int*   in   = (const int*)d_in[0];
  const int*   w    = (const int*)d_in[1];
  const float* bias = (const float*)d_in[2];
  float*       out  = (float*)d_out;

  const size_t WQ_OFF = 0;                        // 294912
  const size_t IP_OFF = 294912;                   // 12845056
  const size_t RS_OFF = IP_OFF + 12845056;        // 401408
  const size_t AF_OFF = RS_OFF + 401408;          // 373248
  const size_t BC_OFF = AF_OFF + 373248;          // 1024
  const size_t NEED   = BC_OFF + 1024;

  if (ws_size >= NEED) {
    char* ws = (char*)d_ws;
    signed char* wq2  = (signed char*)(ws + WQ_OFF);
    signed char* ip   = (signed char*)(ws + IP_OFF);
    int*         rs   = (int*)(ws + RS_OFF);
    float*       af   = (float*)(ws + AF_OFF);
    float*       bc   = (float*)(ws + BC_OFF);

    repack_w<<<C_OUT, 128, 0, stream>>>(w, bias, wq2, bc);
    repack_in<<<dim3(H_IN, N_B), 256, 0, stream>>>(in, ip, rs);
    asum_k<<<(NPX + 255) / 256, 256, 0, stream>>>(rs, af);
    conv_mfma<<<dim3(27, N_B, 2), 256, 0, stream>>>(ip, wq2, af, bc, out);
  } else {
    size_t total = (size_t)N_B * C_OUT * H_OUT * W_OUT;
    conv_naive<<<(total + 255) / 256, 256, 0, stream>>>(in, w, bias, out);
  }
}

// Round 5
// 73.690 us; speedup vs baseline: 2.9453x; 1.0002x over previous
//
#include <hip/hip_runtime.h>
#include <hip/hip_bf16.h>

// Quantized int8 3x3 conv via implicit-im2col MFMA (mfma_i32_16x16x64_i8).
// out = 1e-4*dot + asumf[px] + bconst[co]
//
// Round-5 structure:
//   - block owns 2 output rows (108 px) x 128 couts; grid (27 rowpairs, 32 n, 2 ctile)
//   - input slab (4 rows x 56 x 128 = 28KB) staged ONCE per block, XOR-swizzled
//     (pre-swizzled global source + linear LDS dest; readers apply same XOR)
//   - weights NOT in LDS: step-major wq2[tap][q8][co256][16B] fragments load
//     L2->registers directly (16-lane groups read 256B contiguous)
//   - LDS = 28KB only -> 4 blocks/CU; NO barriers in the 9-tap main loop

#define N_B   32
#define C_IN  128
#define H_IN  56
#define W_IN  56
#define C_OUT 256
#define H_OUT 54
#define W_OUT 54
#define K_TOT 1152
#define NPX   (N_B * H_OUT * W_OUT)   // 93312
#define PXROW (H_OUT * W_OUT)         // 2916

using i32x4 = __attribute__((ext_vector_type(4))) int;

static __device__ __forceinline__ int dot4(int a, int b, int c) {
#if __has_builtin(__builtin_amdgcn_sdot4)
  return __builtin_amdgcn_sdot4(a, b, c, false);
#else
  signed char a0 = (signed char)a, a1 = (signed char)(a >> 8),
              a2 = (signed char)(a >> 16), a3 = (signed char)(a >> 24);
  signed char b0 = (signed char)b, b1 = (signed char)(b >> 8),
              b2 = (signed char)(b >> 16), b3 = (signed char)(b >> 24);
  return c + a0 * b0 + a1 * b1 + a2 * b2 + a3 * b3;
#endif
}

__device__ __forceinline__ void gload16(const void* g, void* l) {
  __builtin_amdgcn_global_load_lds(
      (const __attribute__((address_space(1))) void*)g,
      (__attribute__((address_space(3))) void*)l, 16, 0, 0);
}

// ---------------- weight repack: OIHW(int32) -> wq2[t][q][co][16] i8, bconst
__global__ void repack_w(const int* __restrict__ w, const float* __restrict__ bias,
                         signed char* __restrict__ wq2, float* __restrict__ bconst) {
  int co = blockIdx.x;    // 256
  int ci = threadIdx.x;   // 128
  const int* wrow = w + (size_t)co * K_TOT + (size_t)ci * 9;
  int s = 0;
  int q = ci >> 4, b = ci & 15;
#pragma unroll
  for (int t = 0; t < 9; ++t) {
    int v = wrow[t];
    s += v;
    wq2[(size_t)t * 32768 + q * 4096 + co * 16 + b] = (signed char)v;
  }
  __shared__ int red[128];
  red[ci] = s;
  __syncthreads();
  for (int off = 64; off > 0; off >>= 1) {
    if (ci < off) red[ci] += red[ci + off];
    __syncthreads();
  }
  if (ci == 0) {
    int wsum = red[0];
    float r = rintf(bias[co] / 0.0001f);                 // round half-even
    r = fminf(fmaxf(r, -2147483648.0f), 2147483647.0f);  // clamp to i32 range
    bconst[co] = 1e-4f * (float)(-7 * wsum + 24192) + r * 0.0001f;
  }
}

// ---------------- input repack: NCHW(int32) -> NHWC int8, fused per-px channel sums
__global__ void repack_in(const int* __restrict__ in, signed char* __restrict__ ip,
                          int* __restrict__ rs) {
  __shared__ int t32[C_IN * W_IN];   // 28KB
  __shared__ int rsum[W_IN];
  int h = blockIdx.x, n = blockIdx.y;
  int tid = threadIdx.x;
  if (tid < W_IN) rsum[tid] = 0;

  int ci = tid >> 1, hf = tid & 1;
  const int* s = in + ((size_t)n * C_IN + ci) * (H_IN * W_IN) + h * W_IN + hf * 28;
  int* d = &t32[ci * W_IN + hf * 28];
#pragma unroll
  for (int k = 0; k < 7; ++k)
    *(int4*)(d + k * 4) = *(const int4*)(s + k * 4);
  __syncthreads();

  signed char* dst = ip + (((size_t)n * H_IN + h) * W_IN) * C_IN;
  for (int j = tid; j < 448; j += 256) {
    int w = j >> 3, c16 = j & 7;
    int b[4], srow = 0;
#pragma unroll
    for (int q = 0; q < 4; ++q) {
      int x0 = t32[(c16 * 16 + q * 4 + 0) * W_IN + w];
      int x1 = t32[(c16 * 16 + q * 4 + 1) * W_IN + w];
      int x2 = t32[(c16 * 16 + q * 4 + 2) * W_IN + w];
      int x3 = t32[(c16 * 16 + q * 4 + 3) * W_IN + w];
      b[q] = (x0 & 255) | ((x1 & 255) << 8) | ((x2 & 255) << 16) | ((x3 & 255) << 24);
      srow = dot4(b[q], 0x01010101, srow);
    }
    *(int4*)(dst + (size_t)j * 16) = *(int4*)b;
    atomicAdd(&rsum[w], srow);
  }
  __syncthreads();
  if (tid < W_IN) rs[((size_t)n * H_IN + h) * W_IN + tid] = rsum[tid];
}

// ---------------- per-output-pixel: asumf = -3e-4 * receptive-field sum
__global__ void asum_k(const int* __restrict__ rs, float* __restrict__ asumf) {
  int px = blockIdx.x * 256 + threadIdx.x;
  if (px >= NPX) return;
  int n = px / PXROW, rem = px - n * PXROW;
  int y = rem / W_OUT, x = rem - y * W_OUT;
  const int* rp = rs + ((size_t)n * H_IN + y) * W_IN + x;
  int s = 0;
#pragma unroll
  for (int kh = 0; kh < 3; ++kh)
    s += rp[kh * W_IN + 0] + rp[kh * W_IN + 1] + rp[kh * W_IN + 2];
  asumf[px] = -3e-4f * (float)s;
}

// ---------------- main MFMA conv
__launch_bounds__(256, 4)
__global__ void conv_mfma(const signed char* __restrict__ ip,
                          const signed char* __restrict__ wq2,
                          const float* __restrict__ asumf,
                          const float* __restrict__ bconst,
                          float* __restrict__ out) {
  __shared__ signed char lds[28672];  // B slab only
  const int tid = threadIdx.x, w = tid >> 6, l = tid & 63;
  const int wr = w >> 1, wc = w & 1;
  const int rp = blockIdx.x;           // row pair 0..26
  const int n  = blockIdx.y;           // 0..31
  const int ct = blockIdx.z;           // co tile 0..1
  const int y0 = rp * 2;

  // ---- stage B slab (4 input rows, 28KB), pre-swizzled source, linear dest
  const signed char* slab = ip + ((size_t)(n * H_IN + y0) * W_IN) * C_IN;
  const int sw = ((tid >> 3) & 7) << 4;        // (L>>7)&7 is i-invariant
#pragma unroll
  for (int i = 0; i < 7; ++i) {
    int L = i * 4096 + tid * 16;
    gload16(slab + (L ^ sw), &lds[L]);
  }

  // ---- per-lane B pixel bases (slab px index for each fragment)
  int psb[4];
#pragma unroll
  for (int p = 0; p < 4; ++p) {
    int j = wc * 64 + p * 16 + (l & 15);
    if (j > 107) j = 107;                 // dead lanes clamp (stores guarded)
    int dy = (j >= 54) ? 1 : 0;
    psb[p] = dy * 56 + (j - dy * 54);
  }
  const int c0 = (l >> 4) * 16;

  // ---- A fragment source: co = ct*128 + wr*64 + m*16 + (l&15), q = kk*4 + (l>>4)
  // addr = wq2 + t*32768 + q*4096 + co*16  -> af[m] at awq + t*32768 + kk*16384 + m*256
  const signed char* awq = wq2 + (size_t)(l >> 4) * 4096 +
                           (size_t)(ct * 128 + wr * 64 + (l & 15)) * 16;

  i32x4 acc[4][4];
#pragma unroll
  for (int m = 0; m < 4; ++m)
#pragma unroll
    for (int p = 0; p < 4; ++p) acc[m][p] = (i32x4){0, 0, 0, 0};

  __syncthreads();   // slab staged (drains vmcnt) — the ONLY barrier

#pragma unroll
  for (int t = 0; t < 9; ++t) {
    const int dlt = (t / 3) * 56 + (t % 3);    // tap offset in slab px units
#pragma unroll
    for (int kk = 0; kk < 2; ++kk) {
      i32x4 af[4], bf[4];
#pragma unroll
      for (int m = 0; m < 4; ++m)
        af[m] = *(const i32x4*)(awq + (size_t)t * 32768 + kk * 16384 + m * 256);
#pragma unroll
      for (int p = 0; p < 4; ++p) {
        int ps = psb[p] + dlt;
        int ad = ((ps << 7) + c0 + kk * 64) ^ ((ps & 7) << 4);
        bf[p] = *(const i32x4*)(&lds[ad]);
      }
#pragma unroll
      for (int m = 0; m < 4; ++m)
#pragma unroll
        for (int p = 0; p < 4; ++p)
          acc[m][p] = __builtin_amdgcn_mfma_i32_16x16x64_i8(af[m], bf[p],
                                                            acc[m][p], 0, 0, 0);
    }
  }

  // ---- epilogue: C frag: px col = l&15, co row = (l>>4)*4 + j
  float* obase = out + ((size_t)(n * C_OUT + ct * 128)) * PXROW + y0 * W_OUT;
  const float* apx = asumf + (size_t)n * PXROW + y0 * W_OUT;
  int jv[4]; float asf[4];
#pragma unroll
  for (int p = 0; p < 4; ++p) {
    int j = wc * 64 + p * 16 + (l & 15);
    jv[p] = j;
    asf[p] = (j < 108) ? apx[j] : 0.0f;
  }
#pragma unroll
  for (int m = 0; m < 4; ++m) {
#pragma unroll
    for (int jj = 0; jj < 4; ++jj) {
      int col = wr * 64 + m * 16 + (l >> 4) * 4 + jj;   // co within ctile
      float bc = bconst[ct * 128 + col];
      float* o = obase + (size_t)col * PXROW;
#pragma unroll
      for (int p = 0; p < 4; ++p)
        if (jv[p] < 108)
          o[jv[p]] = 1e-4f * (float)acc[m][p][jj] + asf[p] + bc;
    }
  }
}

// ---------------- fallback (tiny ws): naive direct conv
__global__ void conv_naive(const int* __restrict__ in, const int* __restrict__ w,
                           const float* __restrict__ bias, float* __restrict__ out) {
  size_t idx = (size_t)blockIdx.x * 256 + threadIdx.x;
  size_t total = (size_t)N_B * C_OUT * H_OUT * W_OUT;
  if (idx >= total) return;
  int x = idx % W_OUT; size_t t = idx / W_OUT;
  int y = t % H_OUT; t /= H_OUT;
  int co = t % C_OUT; int n = (int)(t / C_OUT);
  int acc = 0;
  for (int ci = 0; ci < C_IN; ++ci) {
    const int* ib = in + (((size_t)n * C_IN + ci) * H_IN + y) * W_IN + x;
    const int* wb = w + (((size_t)co * C_IN + ci) * 3) * 3;
    for (int kh = 0; kh < 3; ++kh)
      for (int kw = 0; kw < 3; ++kw)
        acc += (ib[kh * W_IN + kw] - 7) * (wb[kh * 3 + kw] - 3);
  }
  float r = rintf(bias[co] / 0.0001f);
  r = fminf(fmaxf(r, -2147483648.0f), 2147483647.0f);
  out[idx] = (float)acc * (0.01f * 0.01f) + r * 0.0001f;
}

extern "C" void kernel_launch(void* const* d_in, const int* in_sizes, int n_in,
                              void* d_out, int out_size, void* d_ws, size_t ws_size,
                              hipStream_t stream) {
  const int*   in   = (const int*)d_in[0];
  const int*   w    = (const int*)d_in[1];
  const float* bias = (const float*)d_in[2];
  float*       out  = (float*)d_out;

  const size_t WQ_OFF = 0;                        // 294912
  const size_t IP_OFF = 294912;                   // 12845056
  const size_t RS_OFF = IP_OFF + 12845056;        // 401408
  const size_t AF_OFF = RS_OFF + 401408;          // 373248
  const size_t BC_OFF = AF_OFF + 373248;          // 1024
  const size_t NEED   = BC_OFF + 1024;

  if (ws_size >= NEED) {
    char* ws = (char*)d_ws;
    signed char* wq2  = (signed char*)(ws + WQ_OFF);
    signed char* ip   = (signed char*)(ws + IP_OFF);
    int*         rs   = (int*)(ws + RS_OFF);
    float*       af   = (float*)(ws + AF_OFF);
    float*       bc   = (float*)(ws + BC_OFF);

    repack_w<<<C_OUT, 128, 0, stream>>>(w, bias, wq2, bc);
    repack_in<<<dim3(H_IN, N_B), 256, 0, stream>>>(in, ip, rs);
    asum_k<<<(NPX + 255) / 256, 256, 0, stream>>>(rs, af);
    conv_mfma<<<dim3(27, N_B, 2), 256, 0, stream>>>(ip, wq2, af, bc, out);
  } else {
    size_t total = (size_t)N_B * C_OUT * H_OUT * W_OUT;
    conv_naive<<<(total + 255) / 256, 256, 0, stream>>>(in, w, bias, out);
  }
}